// Round 6
// baseline (51.660 us; speedup 1.0000x reference)
//
#include <hip/hip_runtime.h>

#define KS   7
#define KK   49
#define MIDJ 24
#define H    256
#define W    320
#define HW   (H * W)
#define BS   4
#define ITERS 6

// R5 DIAGNOSTIC: R0 structure (best, 21.5us) executed `reps` times inside the
// kernel. reps/zero are runtime args (host passes 3 and 0) so the compiler can
// neither unroll-away nor LICM-hoist the loads (all base addresses formally
// depend on rep*zero). Each pass's result is consumed by an empty asm so no
// pass is dead. Output identical to R0 (last pass stored).
// Purpose: (1) make our kernel outrank the harness's 39us poison-fills in the
// rocprof top-5 so we finally see its true duration / FETCH_SIZE / VALUBusy /
// occupancy; (2) solve T_kernel vs per-replay overhead via
// T = (dur_3x - dur_1x)/2 against R0's 21.5us.
__global__ __launch_bounds__(256) void dyspn_probe3x(
    const float* __restrict__ kern,    // (BS, KK, HW)
    const float* __restrict__ input,   // (BS, 1, H, W)
    const float* __restrict__ input0,  // (BS, 1, H, W)
    const float* __restrict__ att,     // (BS, ITERS, 4, HW)
    const int*   __restrict__ i_ptr,   // scalar
    float*       __restrict__ out,     // (BS, 1, H, W)
    int reps, int zero)
{
    const int i_sel = *i_ptr;

    int t   = blockIdx.x * blockDim.x + threadIdx.x;  // 2 pixels per thread
    int idx = t * 2;
    if (idx >= BS * HW) return;

    int b = idx / HW;
    int p = idx - b * HW;          // even
    int y = p / W;
    int x = p - y * W;

    float o0 = 0.f, o1 = 0.f;

    for (int rep = 0; rep < reps; ++rep) {
        const size_t roff = (size_t)(rep * zero);     // 0 at runtime, opaque

        const float* attb = att + roff + ((size_t)(b * ITERS + i_sel)) * 4 * HW + p;
        float2 a0 = *(const float2*)(attb);
        float2 a1 = *(const float2*)(attb + HW);
        float2 a2 = *(const float2*)(attb + 2 * HW);
        float2 a3 = *(const float2*)(attb + 3 * HW);
        const float ar0[4] = {a0.x, a1.x, a2.x, a3.x};
        const float ar1[4] = {a0.y, a1.y, a2.y, a3.y};

        const float* kb  = kern + roff + (size_t)b * KK * HW + p;
        const float* inb = input + roff + (size_t)b * HW;
        float2 mid2 = *(const float2*)(input0 + roff + (size_t)b * HW + p);

        float acc0 = 0.f, acc1 = 0.f, den0 = 0.f, den1 = 0.f;

#pragma unroll
        for (int j = 0; j < KK; ++j) {
            const int dy = j / KS - 3;                   // compile-time
            const int dx = j % KS - 3;                   // compile-time
            const int r  = max(dy < 0 ? -dy : dy,
                               dx < 0 ? -dx : dx);       // ring id, compile-time

            float2 kv = *(const float2*)(kb + (size_t)j * HW);
            float v0 = kv.x * ar0[r];
            float v1 = kv.y * ar1[r];
            den0 += fabsf(v0);
            den1 += fabsf(v1);

            float p0, p1;
            if (j == MIDJ) {
                p0 = mid2.x; p1 = mid2.y;
            } else {
                const int yy = y + dy;
                if (yy >= 0 && yy < H) {
                    const int x0 = x + dx;
                    const int x1 = x0 + 1;
                    const float* row = inb + yy * W;
                    p0 = (x0 >= 0 && x0 < W) ? row[x0] : 0.f;
                    p1 = (x1 >= 0 && x1 < W) ? row[x1] : 0.f;
                } else {
                    p0 = 0.f; p1 = 0.f;
                }
            }
            acc0 = fmaf(v0, p0, acc0);
            acc1 = fmaf(v1, p1, acc1);
        }

        o0 = acc0 / den0;
        o1 = acc1 / den1;
        asm volatile("" :: "v"(o0), "v"(o1));   // keep every pass live
    }

    float2 o;
    o.x = o0;
    o.y = o1;
    *(float2*)(out + (size_t)b * HW + p) = o;
}

extern "C" void kernel_launch(void* const* d_in, const int* in_sizes, int n_in,
                              void* d_out, int out_size, void* d_ws, size_t ws_size,
                              hipStream_t stream) {
    const float* kern   = (const float*)d_in[0];
    const float* input  = (const float*)d_in[1];
    const float* input0 = (const float*)d_in[2];
    const float* att    = (const float*)d_in[3];
    const int*   i_ptr  = (const int*)d_in[4];
    float* out = (float*)d_out;

    const int total_threads = BS * HW / 2;   // 163840
    const int block = 256;
    const int grid  = (total_threads + block - 1) / block;  // 640

    dyspn_probe3x<<<grid, block, 0, stream>>>(kern, input, input0, att, i_ptr, out,
                                              3, 0);
}

// Round 7
// 24.554 us; speedup vs baseline: 2.1040x; 2.1040x over previous
//
#include <hip/hip_runtime.h>

#define KS   7
#define KK   49
#define MIDJ 24
#define H    256
#define W    320
#define HW   (H * W)
#define BS   4
#define ITERS 6

#define PB   256              // pixels (= threads) per block
#define BPB  (HW / PB)        // 320 blocks per image
#define DR   16               // LDS ring slots (1 KB each)
#define NFL  15               // kern planes in flight per wave
#define TW   328              // input tile row stride (zero-padded +/-4)
#define TR   8                // tile rows: y0-3 .. y0+4
#define TFL  (TR * TW)        // 2624 floats

typedef __attribute__((address_space(3))) unsigned       lds_u32_t;
typedef const __attribute__((address_space(1))) unsigned glb_u32_t;

// counted vmcnt waits (literal immediates), with "memory" so LDS reads can't
// be hoisted above them (guide rule #18 analog: C-level ds_reads ARE ordered
// by the memory clobber).
template<int N> __device__ __forceinline__ void waitv();
#define WVDEF(n) template<> __device__ __forceinline__ void waitv<n>() { \
    asm volatile("s_waitcnt vmcnt(" #n ")" ::: "memory"); }
WVDEF(0) WVDEF(1) WVDEF(2) WVDEF(3) WVDEF(4) WVDEF(5) WVDEF(6) WVDEF(7)
WVDEF(8) WVDEF(9) WVDEF(10) WVDEF(11) WVDEF(12) WVDEF(13) WVDEF(14) WVDEF(15)

__device__ __forceinline__ void dma4(const float* g, float* l) {
    // 4 B/lane direct global->LDS; LDS dest = wave-uniform base + lane*4.
    __builtin_amdgcn_global_load_lds((glb_u32_t*)g, (lds_u32_t*)l, 4, 0, 0);
}

struct Ctx {
    const float* kbl;      // kern + b*KK*HW + p0 + tid   (per-lane, plane j at +j*HW)
    float*       ringw;    // ring + (tid & 192)          (wave-uniform slot base)
    const float* ring_rd;  // ring + tid
    const float* tile_rd;  // tile + tbm (all 49 offsets >= 0)
    float ar0, ar1, ar2, ar3, mid;
};

template<int J>
struct KStep {
    static __device__ __forceinline__ void run(const Ctx& c, float& acc, float& den) {
        constexpr int dy = J / KS - 3;
        constexpr int dx = J % KS - 3;
        constexpr int ady = dy < 0 ? -dy : dy;
        constexpr int adx = dx < 0 ? -dx : dx;
        constexpr int r   = ady > adx ? ady : adx;          // ring id
        constexpr int slot = J % DR;
        constexpr int KC = (J <= 34) ? (NFL - 1) : (KK - 1 - J);  // counted wait

        waitv<KC>();                                        // plane J arrived
        float kv = c.ring_rd[slot * PB];                    // ds_read_b32 imm-offset
        float a  = (r == 0) ? c.ar0 : (r == 1) ? c.ar1 : (r == 2) ? c.ar2 : c.ar3;
        float v  = kv * a;
        den += fabsf(v);
        float pv = (J == MIDJ) ? c.mid
                               : c.tile_rd[(dy + 3) * TW + (dx + 3)];
        acc = fmaf(v, pv, acc);

        if constexpr (J + NFL < KK) {                       // prefetch plane J+15
            constexpr int jn = J + NFL;
            dma4(c.kbl + (size_t)jn * HW, c.ringw + (jn % DR) * PB);
        }
        KStep<J + 1>::run(c, acc, den);
    }
};
template<> struct KStep<KK> {
    static __device__ __forceinline__ void run(const Ctx&, float&, float&) {}
};

__global__ __launch_bounds__(PB) void dyspn_dma(
    const float* __restrict__ kern,    // (BS, KK, HW)
    const float* __restrict__ input,   // (BS, H, W)
    const float* __restrict__ input0,  // (BS, H, W)
    const float* __restrict__ att,     // (BS, ITERS, 4, HW)
    const int*   __restrict__ i_ptr,
    float*       __restrict__ out)     // (BS, H, W)
{
    __shared__ float ring[DR * PB];    // 16 KB kern ring
    __shared__ float tile[TFL];        // 10.25 KB padded input tile

    const int tid = threadIdx.x;
    const int bid = blockIdx.x;
    const int b   = bid / BPB;
    const int p0  = (bid - b * BPB) * PB;
    const int p   = p0 + tid;
    const int y   = p / W;
    const int x   = p - y * W;
    const int y0  = p0 / W;

    const int i_sel = *i_ptr;

    // early register loads, forced live so their waits precede the DMA queue
    const float* ab = att + ((size_t)(b * ITERS + i_sel)) * 4 * HW + p;
    float ar0 = ab[0], ar1 = ab[HW], ar2 = ab[2 * HW], ar3 = ab[3 * HW];
    float mid = input0[(size_t)b * HW + p];
    asm volatile("" :: "v"(ar0), "v"(ar1), "v"(ar2), "v"(ar3), "v"(mid));

    // stage zero-padded input tile: rows y0-3..y0+4, cols -4..323
    #pragma unroll
    for (int k = 0; k < (TFL + PB - 1) / PB; ++k) {
        int idx = tid + k * PB;
        if (idx < TFL) {
            int rr = idx / TW;
            int cc = idx - rr * TW;
            int gy = y0 - 3 + rr;
            int gx = cc - 4;
            float v = 0.f;
            if (gy >= 0 && gy < H && gx >= 0 && gx < W)
                v = input[(size_t)b * HW + gy * W + gx];
            tile[idx] = v;
        }
    }
    __syncthreads();   // drains vmcnt to 0 -> clean counter for the ring

    Ctx c;
    c.kbl     = kern + (size_t)b * KK * HW + p0 + tid;
    c.ringw   = ring + (tid & 192);
    c.ring_rd = ring + tid;
    {
        const int tb = ((y - y0) + 3) * TW + (x + 4);
        c.tile_rd = tile + (tb - 3 * TW - 3);   // >=1, max offset fits tile
    }
    c.ar0 = ar0; c.ar1 = ar1; c.ar2 = ar2; c.ar3 = ar3; c.mid = mid;

    // DMA prologue: planes 0..14 into slots 0..14
    #pragma unroll
    for (int jp = 0; jp < NFL; ++jp)
        dma4(c.kbl + (size_t)jp * HW, c.ringw + jp * PB);

    float acc = 0.f, den = 0.f;
    KStep<0>::run(c, acc, den);

    out[(size_t)b * HW + p] = acc / den;
}

extern "C" void kernel_launch(void* const* d_in, const int* in_sizes, int n_in,
                              void* d_out, int out_size, void* d_ws, size_t ws_size,
                              hipStream_t stream) {
    const float* kern   = (const float*)d_in[0];
    const float* input  = (const float*)d_in[1];
    const float* input0 = (const float*)d_in[2];
    const float* att    = (const float*)d_in[3];
    const int*   i_ptr  = (const int*)d_in[4];
    float* out = (float*)d_out;

    const int grid = BS * BPB;   // 1280 blocks, 5 per CU, all co-resident
    dyspn_dma<<<grid, PB, 0, stream>>>(kern, input, input0, att, i_ptr, out);
}

// Round 8
// 21.584 us; speedup vs baseline: 2.3934x; 1.1376x over previous
//
#include <hip/hip_runtime.h>

#define KS   7
#define KK   49
#define MIDJ 24
#define H    256
#define W    320
#define HW   (H * W)
#define BS   4
#define ITERS 6

// R8 = R0 restored (best measured: 21.5 us). Five structural variants
// (scalar/float2/float4 loads, 5-20 waves/CU, pad-prekernel, nontemporal,
// LDS DMA ring with counted vmcnt) all land at 21.5-25 us ~= 3.5-3.9 TB/s
// read. Working set is L3-resident during timed replays (probe FETCH_SIZE
// = 18 MB/rep); the convergence value matches the IC->L2 fill-path ceiling
// (~0.5 TB/s/XCD * 8). Traffic is irreducible (kern = 64 MB, read once).
// Floor ~= 71 MB / 3.9 TB/s + 2.5 us overhead ~= 20.7 us; this kernel is
// within ~4% of it.
__global__ __launch_bounds__(256) void dyspn_kernel(
    const float* __restrict__ kern,    // (BS, KK, HW)
    const float* __restrict__ input,   // (BS, 1, H, W)
    const float* __restrict__ input0,  // (BS, 1, H, W)
    const float* __restrict__ att,     // (BS, ITERS, 4, HW)
    const int*   __restrict__ i_ptr,   // scalar
    float*       __restrict__ out)     // (BS, 1, H, W)
{
    const int i_sel = *i_ptr;

    int t   = blockIdx.x * blockDim.x + threadIdx.x;  // 2 pixels per thread
    int idx = t * 2;
    if (idx >= BS * HW) return;

    int b = idx / HW;
    int p = idx - b * HW;          // even
    int y = p / W;
    int x = p - y * W;

    // attention[b, i_sel, r, p..p+1]
    const float* attb = att + ((size_t)(b * ITERS + i_sel)) * 4 * HW + p;
    float2 a0 = *(const float2*)(attb);
    float2 a1 = *(const float2*)(attb + HW);
    float2 a2 = *(const float2*)(attb + 2 * HW);
    float2 a3 = *(const float2*)(attb + 3 * HW);
    const float ar0[4] = {a0.x, a1.x, a2.x, a3.x};
    const float ar1[4] = {a0.y, a1.y, a2.y, a3.y};

    const float* kb  = kern + (size_t)b * KK * HW + p;
    const float* inb = input + (size_t)b * HW;

    float acc0 = 0.f, acc1 = 0.f, den0 = 0.f, den1 = 0.f;

#pragma unroll
    for (int j = 0; j < KK; ++j) {
        const int dy = j / KS - 3;                       // compile-time
        const int dx = j % KS - 3;                       // compile-time
        const int r  = max(dy < 0 ? -dy : dy,
                           dx < 0 ? -dx : dx);           // ring id, compile-time

        float2 kv = *(const float2*)(kb + (size_t)j * HW);
        float v0 = kv.x * ar0[r];
        float v1 = kv.y * ar1[r];
        den0 += fabsf(v0);
        den1 += fabsf(v1);

        float p0, p1;
        if (j == MIDJ) {
            float2 z = *(const float2*)(input0 + (size_t)b * HW + p);
            p0 = z.x; p1 = z.y;
        } else {
            const int yy = y + dy;
            if (yy >= 0 && yy < H) {
                const int x0 = x + dx;
                const int x1 = x0 + 1;
                const float* row = inb + yy * W;
                p0 = (x0 >= 0 && x0 < W) ? row[x0] : 0.f;
                p1 = (x1 >= 0 && x1 < W) ? row[x1] : 0.f;
            } else {
                p0 = 0.f; p1 = 0.f;
            }
        }
        acc0 += v0 * p0;
        acc1 += v1 * p1;
    }

    float2 o;
    o.x = acc0 / den0;
    o.y = acc1 / den1;
    *(float2*)(out + (size_t)b * HW + p) = o;
}

extern "C" void kernel_launch(void* const* d_in, const int* in_sizes, int n_in,
                              void* d_out, int out_size, void* d_ws, size_t ws_size,
                              hipStream_t stream) {
    const float* kern   = (const float*)d_in[0];
    const float* input  = (const float*)d_in[1];
    const float* input0 = (const float*)d_in[2];
    const float* att    = (const float*)d_in[3];
    const int*   i_ptr  = (const int*)d_in[4];
    float* out = (float*)d_out;

    const int total_threads = BS * HW / 2;   // 163840
    const int block = 256;
    const int grid  = (total_threads + block - 1) / block;  // 640

    dyspn_kernel<<<grid, block, 0, stream>>>(kern, input, input0, att, i_ptr, out);
}